// Round 2
// baseline (1169.758 us; speedup 1.0000x reference)
//
#include <hip/hip_runtime.h>

#define N_NODES 20000
#define N_EDGES 640000
#define NODE_NF 256
#define EDGE_NF 128
#define OUT_NF  256

typedef short v8s __attribute__((ext_vector_type(8)));
typedef float v4f __attribute__((ext_vector_type(4)));

__device__ __forceinline__ float bf2f(unsigned short h) {
    unsigned int u = ((unsigned int)h) << 16;
    return __builtin_bit_cast(float, u);
}
__device__ __forceinline__ unsigned short f2bf(float f) {
    unsigned int u = __builtin_bit_cast(unsigned int, f);
    u = (u + 0x7FFFu + ((u >> 16) & 1u)) >> 16;  // round-to-nearest-even
    return (unsigned short)u;
}
// two float4 -> one bf16x8 fragment
__device__ __forceinline__ v8s cvt8(v4f lo, v4f hi) {
    v8s r;
    #pragma unroll
    for (int j = 0; j < 4; ++j) {
        r[j]     = (short)f2bf(lo[j]);
        r[4 + j] = (short)f2bf(hi[j]);
    }
    return r;
}

// ---------------------------------------------------------------------------
// K1: P_i = node_feats @ W_i ; P_j = node_feats @ W_j
// fp32 in -> bf16 MFMA -> bf16 P tables in d_ws.
// Block = 256 (4 waves). Tile = 16 nodes; wave 0/1 -> P_i cols 0-127/128-255,
// wave 2/3 -> same for P_j. MFMA 16x16x32 bf16.
// A-frag: m=lane&15, k=quad*8+j (8 consecutive fp32 -> 2x float4 -> cvt).
// B-frag: n=lane&15, k=quad*8+j (strided fp32 scalar loads; W is L2-hot).
// ---------------------------------------------------------------------------
__global__ __launch_bounds__(256) void node_proj_kernel(
    const float* __restrict__ node_feats,
    const float* __restrict__ W_i,
    const float* __restrict__ W_j,
    unsigned short* __restrict__ P_i,
    unsigned short* __restrict__ P_j)
{
    const int n0   = blockIdx.x * 16;          // 20000 = 16 * 1250
    const int wave = threadIdx.x >> 6;
    const int lane = threadIdx.x & 63;
    const int m    = lane & 15;
    const int quad = lane >> 4;

    const float*    W = (wave >= 2) ? W_j : W_i;
    unsigned short* P = (wave >= 2) ? P_j : P_i;
    const int colbase = (wave & 1) * 128;

    v4f acc[8];
    #pragma unroll
    for (int i = 0; i < 8; ++i) acc[i] = (v4f)(0.0f);

    for (int kt = 0; kt < 8; ++kt) {           // K = 256 = 8 * 32
        const int krow = kt * 32 + quad * 8;
        const float* arow = node_feats + (size_t)(n0 + m) * NODE_NF + krow;
        v8s afrag = cvt8(*reinterpret_cast<const v4f*>(arow),
                         *reinterpret_cast<const v4f*>(arow + 4));
        #pragma unroll
        for (int nt = 0; nt < 8; ++nt) {
            const int n = colbase + nt * 16 + m;
            v8s bfrag;
            #pragma unroll
            for (int j = 0; j < 8; ++j)
                bfrag[j] = (short)f2bf(W[(size_t)(krow + j) * OUT_NF + n]);
            acc[nt] = __builtin_amdgcn_mfma_f32_16x16x32_bf16(afrag, bfrag, acc[nt], 0, 0, 0);
        }
    }

    // C/D layout: col = lane&15, row = quad*4 + reg
    #pragma unroll
    for (int nt = 0; nt < 8; ++nt) {
        const int n = colbase + nt * 16 + m;
        #pragma unroll
        for (int r = 0; r < 4; ++r) {
            const int row = quad * 4 + r;
            P[(size_t)(n0 + row) * OUT_NF + n] = f2bf(acc[nt][r]);
        }
    }
}

// ---------------------------------------------------------------------------
// K2: out[e] = relu(edge_attr[e] @ W_ij + b + P_i[src[e]] + P_j[dst[e]])
// Grid-strided 16-edge tiles. W_ij bf16 fragments in registers (64 VGPRs,
// loaded once). Per tile: stage S[16][256] = P_i[src]+P_j[dst]+b in LDS fp32
// (stride 260 kills epilogue bank conflicts), 16 MFMAs/wave, relu, fp32 store.
// ---------------------------------------------------------------------------
__global__ __launch_bounds__(256) void edge_kernel(
    const float* __restrict__ edge_attr,
    const int*   __restrict__ edge_index,
    const float* __restrict__ W_ij,
    const float* __restrict__ bias,
    const unsigned short* __restrict__ P_i,
    const unsigned short* __restrict__ P_j,
    float*       __restrict__ out,
    int num_tiles)
{
    __shared__ float S[16][260];

    const int wave  = threadIdx.x >> 6;
    const int lane  = threadIdx.x & 63;
    const int m     = lane & 15;
    const int quad  = lane >> 4;
    const int wcol0 = wave * 64;

    // Preload W_ij fragments (K=128 -> 4 ktiles; wave covers 64 cols -> 4 ntiles)
    v8s wf[4][4];
    #pragma unroll
    for (int kt = 0; kt < 4; ++kt) {
        const int krow = kt * 32 + quad * 8;
        #pragma unroll
        for (int nt = 0; nt < 4; ++nt) {
            const int n = wcol0 + nt * 16 + m;
            #pragma unroll
            for (int j = 0; j < 8; ++j)
                wf[kt][nt][j] = (short)f2bf(W_ij[(size_t)(krow + j) * OUT_NF + n]);
        }
    }

    // staging mapping: thread covers 16 cols of one edge row
    const int s_edge = threadIdx.x & 15;         // 0..15
    const int s_c0   = (threadIdx.x >> 4) * 16;  // 0,16,...,240

    for (int tile = blockIdx.x; tile < num_tiles; tile += gridDim.x) {
        const int e0 = tile * 16;

        // ---- stage S = P_i[src] + P_j[dst] + bias (fp32) ----
        {
            const int src = edge_index[e0 + s_edge];
            const int dst = edge_index[N_EDGES + e0 + s_edge];
            const unsigned short* pi = P_i + (size_t)src * OUT_NF + s_c0;
            const unsigned short* pj = P_j + (size_t)dst * OUT_NF + s_c0;
            const float* bp = bias + s_c0;
            v8s pi0 = *reinterpret_cast<const v8s*>(pi);
            v8s pi1 = *reinterpret_cast<const v8s*>(pi + 8);
            v8s pj0 = *reinterpret_cast<const v8s*>(pj);
            v8s pj1 = *reinterpret_cast<const v8s*>(pj + 8);
            v4f b0 = *reinterpret_cast<const v4f*>(bp);
            v4f b1 = *reinterpret_cast<const v4f*>(bp + 4);
            v4f b2 = *reinterpret_cast<const v4f*>(bp + 8);
            v4f b3 = *reinterpret_cast<const v4f*>(bp + 12);
            #pragma unroll
            for (int c = 0; c < 4; ++c) {
                S[s_edge][s_c0 + c]      = bf2f((unsigned short)pi0[c])     + bf2f((unsigned short)pj0[c])     + b0[c];
                S[s_edge][s_c0 + 4 + c]  = bf2f((unsigned short)pi0[4 + c]) + bf2f((unsigned short)pj0[4 + c]) + b1[c];
                S[s_edge][s_c0 + 8 + c]  = bf2f((unsigned short)pi1[c])     + bf2f((unsigned short)pj1[c])     + b2[c];
                S[s_edge][s_c0 + 12 + c] = bf2f((unsigned short)pi1[4 + c]) + bf2f((unsigned short)pj1[4 + c]) + b3[c];
            }
        }
        __syncthreads();

        // ---- MFMA: [16 edges x 128] @ [128 x 256] ----
        v4f acc[4];
        #pragma unroll
        for (int i = 0; i < 4; ++i) acc[i] = (v4f)(0.0f);
        #pragma unroll
        for (int kt = 0; kt < 4; ++kt) {
            const float* arow = edge_attr + (size_t)(e0 + m) * EDGE_NF + kt * 32 + quad * 8;
            v8s afrag = cvt8(*reinterpret_cast<const v4f*>(arow),
                             *reinterpret_cast<const v4f*>(arow + 4));
            #pragma unroll
            for (int nt = 0; nt < 4; ++nt)
                acc[nt] = __builtin_amdgcn_mfma_f32_16x16x32_bf16(afrag, wf[kt][nt], acc[nt], 0, 0, 0);
        }

        // ---- epilogue: add S, relu, fp32 store ----
        #pragma unroll
        for (int nt = 0; nt < 4; ++nt) {
            const int col = wcol0 + nt * 16 + m;
            #pragma unroll
            for (int r = 0; r < 4; ++r) {
                const int row = quad * 4 + r;
                float v = acc[nt][r] + S[row][col];
                v = v > 0.0f ? v : 0.0f;
                out[(size_t)(e0 + row) * OUT_NF + col] = v;
            }
        }
        __syncthreads();  // S reused next iteration
    }
}

extern "C" void kernel_launch(void* const* d_in, const int* in_sizes, int n_in,
                              void* d_out, int out_size, void* d_ws, size_t ws_size,
                              hipStream_t stream) {
    const float* node_feats = (const float*)d_in[0]; // [20000,256] fp32
    const int*   edge_index = (const int*)d_in[1];   // [2,640000] int32
    const float* edge_attr  = (const float*)d_in[2]; // [640000,128] fp32
    const float* W_ij       = (const float*)d_in[3]; // [128,256] fp32
    const float* b_ij       = (const float*)d_in[4]; // [256] fp32
    const float* W_i        = (const float*)d_in[5]; // [256,256] fp32
    const float* W_j        = (const float*)d_in[6]; // [256,256] fp32
    float*       out        = (float*)d_out;         // [640000,256] fp32

    unsigned short* P_i = (unsigned short*)d_ws;                  // 10.24 MB bf16
    unsigned short* P_j = P_i + (size_t)N_NODES * OUT_NF;         // 10.24 MB bf16

    node_proj_kernel<<<N_NODES / 16, 256, 0, stream>>>(node_feats, W_i, W_j, P_i, P_j);
    edge_kernel<<<2560, 256, 0, stream>>>(edge_attr, edge_index, W_ij, b_ij,
                                          P_i, P_j, out, N_EDGES / 16);
}